// Round 9
// baseline (31.986 us; speedup 1.0000x reference)
//
#include <hip/hip_runtime.h>
#include <math.h>

#define DIM  4096
#define KOUT 10
#define BATCH 4096
#define NBLK 2048    // 2 rows per wave: row b and row b+NBLK

typedef float float2v __attribute__((ext_vector_type(2)));

// XOR-swizzle on linear LDS float index (verified R1/R4/R6/R8).
__device__ __forceinline__ int swzAddr(int lin) {
    return lin ^ (((lin >> 6) & 7) << 2);
}

__device__ __forceinline__ float rlane(float v, int lane) {
    return __int_as_float(__builtin_amdgcn_readlane(__float_as_int(v), lane));
}

// Drain all pending LDS ops (necessity verified R6: same-wave LDS WAR —
// ds_write may clobber rows whose prior ds_read hasn't returned; compiler
// only fences before USES of loaded data, never before ds_writes).
__device__ __forceinline__ void ldsFence() {
    __builtin_amdgcn_sched_barrier(0);
    asm volatile("s_waitcnt lgkmcnt(0)" ::: "memory");
    __builtin_amdgcn_sched_barrier(0);
}

// Packed RY lifting layer on scalar state bit KP+1 (verified R8).
template<int KP>
__device__ __forceinline__ void liftPk(float2v r2[32], float t, float s) {
    const float2v tv = { -t, -t };
    const float2v sv = {  s,  s };
#pragma unroll
    for (int m = 0; m < 16; ++m) {
        const int i0 = ((m >> KP) << (KP + 1)) | (m & ((1 << KP) - 1));
        const int i1 = i0 | (1 << KP);
        float2v a = r2[i0], b = r2[i1];
        float2v a1 = __builtin_elementwise_fma(tv, b, a);
        float2v b1 = __builtin_elementwise_fma(sv, a1, b);
        r2[i1] = b1;
        r2[i0] = __builtin_elementwise_fma(tv, b1, a1);
    }
}

// Scalar RY lifting layer on state bit 0 (verified R8).
__device__ __forceinline__ void liftIntra(float2v r2[32], float t, float s) {
#pragma unroll
    for (int m = 0; m < 32; ++m) {
        float a = r2[m].x, b = r2[m].y;
        float a1 = fmaf(-t, b, a);
        float b1 = fmaf(s, a1, b);
        r2[m].x = fmaf(-t, b1, a1);
        r2[m].y = b1;
    }
}

// Write this lane's 64 scalars as LDS row `row` (b128, swizzled).
__device__ __forceinline__ void writeRow(float* lds, int row, const float2v* r2) {
#pragma unroll
    for (int e4 = 0; e4 < 16; ++e4)
        *reinterpret_cast<float4*>(&lds[swzAddr(row * 64 + e4 * 4)]) =
            make_float4(r2[2 * e4].x, r2[2 * e4].y,
                        r2[2 * e4 + 1].x, r2[2 * e4 + 1].y);
}

// Paired 8 KB time-shared transposes for two rows in separate LDS slices.
// Scalar semantics per row (verified R6/R8): r_new[j]@lane l = r_old[l]@lane j.
// A's reads overlap B's writes (independent slices); fences protect the
// phase-0-read -> phase-1-write WAR within each slice.
__device__ __forceinline__ void transposePair(float2v rA[32], float2v rB[32],
                                              float* ldsA, float* ldsB, int l) {
    float tA[32], tB[32];
    ldsFence();                 // conservative: vs. any prior pending LDS reads
    if (l < 32) { writeRow(ldsA, l, rA); writeRow(ldsB, l, rB); }
#pragma unroll
    for (int j = 0; j < 32; ++j) tA[j] = ldsA[swzAddr(j * 64 + l)];
#pragma unroll
    for (int j = 0; j < 32; ++j) tB[j] = ldsB[swzAddr(j * 64 + l)];
    ldsFence();                 // WAR: phase-0 reads must land before overwrite
    if (l >= 32) { writeRow(ldsA, l - 32, rA); writeRow(ldsB, l - 32, rB); }
#pragma unroll
    for (int m = 0; m < 16; ++m) {                  // new scalars 32..63, row A
        float2v w;
        w.x = ldsA[swzAddr((2 * m) * 64 + l)];
        w.y = ldsA[swzAddr((2 * m + 1) * 64 + l)];
        rA[16 + m] = w;
    }
#pragma unroll
    for (int m = 0; m < 16; ++m) {                  // new scalars 32..63, row B
        float2v w;
        w.x = ldsB[swzAddr((2 * m) * 64 + l)];
        w.y = ldsB[swzAddr((2 * m + 1) * 64 + l)];
        rB[16 + m] = w;
    }
#pragma unroll
    for (int m = 0; m < 16; ++m) { float2v w; w.x = tA[2*m]; w.y = tA[2*m+1]; rA[m] = w; }
#pragma unroll
    for (int m = 0; m < 16; ++m) { float2v w; w.x = tB[2*m]; w.y = tB[2*m+1]; rB[m] = w; }
}

// Measurement tree (verified R7/R8): d = l*64 + j; qubit k<6 = j-bit k,
// qubits 6-9 = lane bits 0-3. Produces v[0..9] (pre-reduction).
__device__ __forceinline__ void measure(float2v r2[32], int l, float v[10]) {
#pragma unroll
    for (int m = 0; m < 32; ++m) r2[m] *= r2[m];
    float v0 = 0.f, v1 = 0.f, v2 = 0.f, v3 = 0.f, v4 = 0.f;
    float q32[32];
#pragma unroll
    for (int m = 0; m < 32; ++m) { v0 += r2[m].y; q32[m] = r2[m].x + r2[m].y; }
    float q16[16];
#pragma unroll
    for (int m = 0; m < 16; ++m) { v1 += q32[2*m+1]; q16[m] = q32[2*m] + q32[2*m+1]; }
    float q8[8];
#pragma unroll
    for (int m = 0; m < 8; ++m)  { v2 += q16[2*m+1]; q8[m] = q16[2*m] + q16[2*m+1]; }
    float q4[4];
#pragma unroll
    for (int m = 0; m < 4; ++m)  { v3 += q8[2*m+1]; q4[m] = q8[2*m] + q8[2*m+1]; }
    float q2[2];
#pragma unroll
    for (int m = 0; m < 2; ++m)  { v4 += q4[2*m+1]; q2[m] = q4[2*m] + q4[2*m+1]; }
    const float v5   = q2[1];
    const float psum = q2[0] + q2[1];
    v[0] = v0; v[1] = v1; v[2] = v2; v[3] = v3; v[4] = v4; v[5] = v5;
    v[6] = (l & 1) ? psum : 0.f;
    v[7] = (l & 2) ? psum : 0.f;
    v[8] = (l & 4) ? psum : 0.f;
    v[9] = (l & 8) ? psum : 0.f;
}

__global__ __launch_bounds__(64, 2) void vqc_kernel(
        const float* __restrict__ x,
        const float* __restrict__ theta,
        float* __restrict__ out)
{
    __shared__ __align__(16) float lds[2 * 2048];   // 16 KB: slice per row
    const int l = threadIdx.x;
    const int b = blockIdx.x;                        // rows b and b+NBLK
    float* ldsA = lds;
    float* ldsB = lds + 2048;

    // Gate params (shared by both rows). RY(theta) rotates by phi = theta/2:
    // t = tan(theta/4), s = sin(theta/2); alt branch -R(phi) keeps |t|<=1.
    float th = theta[l < 24 ? l : 0];
    float qh = 0.25f * th;
    float sq = sinf(qh), cq = cosf(qh);
    float sfull = 2.f * sq * cq;                     // sin(theta/2)
    float tt, ss;
    if (fabsf(sq) <= fabsf(cq)) { tt = sq / cq;  ss = sfull;  }
    else                        { tt = -cq / sq; ss = -sfull; }

    // ---- direct loads, both rows (32 dwordx4 in flight) ----
    float2v rA[32], rB[32];
    const float4* xA = reinterpret_cast<const float4*>(x + (size_t)b * DIM + l * 64);
    const float4* xB = reinterpret_cast<const float4*>(x + (size_t)(b + NBLK) * DIM + l * 64);
#pragma unroll
    for (int e4 = 0; e4 < 16; ++e4) {
        const float4 w = xA[e4];
        float2v lo; lo.x = w.x; lo.y = w.y;
        float2v hi; hi.x = w.z; hi.y = w.w;
        rA[2 * e4] = lo; rA[2 * e4 + 1] = hi;
    }
#pragma unroll
    for (int e4 = 0; e4 < 16; ++e4) {
        const float4 w = xB[e4];
        float2v lo; lo.x = w.x; lo.y = w.y;
        float2v hi; hi.x = w.z; hi.y = w.w;
        rB[2 * e4] = lo; rB[2 * e4 + 1] = hi;
    }

    // ---- pass 1: qubits 0-5, layer 1 (interleaved A/B chains) ----
    liftIntra (rA, rlane(tt, 0), rlane(ss, 0));  liftIntra (rB, rlane(tt, 0), rlane(ss, 0));
    liftPk<0>(rA, rlane(tt, 1), rlane(ss, 1));   liftPk<0>(rB, rlane(tt, 1), rlane(ss, 1));
    liftPk<1>(rA, rlane(tt, 2), rlane(ss, 2));   liftPk<1>(rB, rlane(tt, 2), rlane(ss, 2));
    liftPk<2>(rA, rlane(tt, 3), rlane(ss, 3));   liftPk<2>(rB, rlane(tt, 3), rlane(ss, 3));
    liftPk<3>(rA, rlane(tt, 4), rlane(ss, 4));   liftPk<3>(rB, rlane(tt, 4), rlane(ss, 4));
    liftPk<4>(rA, rlane(tt, 5), rlane(ss, 5));   liftPk<4>(rB, rlane(tt, 5), rlane(ss, 5));

    transposePair(rA, rB, ldsA, ldsB, l);        // scalar bit k = qubit 6+k

    // ---- pass 2: qubits 6-11, layer 1 ----
    liftIntra (rA, rlane(tt, 6),  rlane(ss, 6));  liftIntra (rB, rlane(tt, 6),  rlane(ss, 6));
    liftPk<0>(rA, rlane(tt, 7),  rlane(ss, 7));   liftPk<0>(rB, rlane(tt, 7),  rlane(ss, 7));
    liftPk<1>(rA, rlane(tt, 8),  rlane(ss, 8));   liftPk<1>(rB, rlane(tt, 8),  rlane(ss, 8));
    liftPk<2>(rA, rlane(tt, 9),  rlane(ss, 9));   liftPk<2>(rB, rlane(tt, 9),  rlane(ss, 9));
    liftPk<3>(rA, rlane(tt, 10), rlane(ss, 10));  liftPk<3>(rB, rlane(tt, 10), rlane(ss, 10));
    liftPk<4>(rA, rlane(tt, 11), rlane(ss, 11));  liftPk<4>(rB, rlane(tt, 11), rlane(ss, 11));

    // CZ diagonal (verified R6/R8): lane bits = qubits 0-5, scalar bits e = 6-11.
    {
        int f  = __popc(l & (l >> 1) & 0x1F) & 1;  // pairs among qubits 0-5
        int l5 = (l >> 5) & 1, l0 = l & 1;
        float sg0 = f              ? -1.f : 1.f;
        float sg1 = (f ^ l5)       ? -1.f : 1.f;   // e0=1: pair (5,6)
        float sg2 = (f ^ l0)       ? -1.f : 1.f;   // e5=1: pair (0,11)
        float sg3 = (f ^ l5 ^ l0)  ? -1.f : 1.f;
#pragma unroll
        for (int e = 0; e < 64; ++e) {
            const int Ce  = __popc(e & (e >> 1) & 0x1F) & 1;  // pairs among 6-11
            const int sel = (e & 1) | (((e >> 5) & 1) << 1);
            float sgn;
            if      (sel == 0) sgn = sg0;
            else if (sel == 1) sgn = sg1;
            else if (sel == 2) sgn = sg2;
            else               sgn = sg3;
            const float m = Ce ? -sgn : sgn;
            if (e & 1) { rA[e >> 1].y *= m; rB[e >> 1].y *= m; }
            else       { rA[e >> 1].x *= m; rB[e >> 1].x *= m; }
        }
    }

    // ---- layer 2 on qubits 6-11 (theta[18..23]) ----
    liftIntra (rA, rlane(tt, 18), rlane(ss, 18)); liftIntra (rB, rlane(tt, 18), rlane(ss, 18));
    liftPk<0>(rA, rlane(tt, 19), rlane(ss, 19));  liftPk<0>(rB, rlane(tt, 19), rlane(ss, 19));
    liftPk<1>(rA, rlane(tt, 20), rlane(ss, 20));  liftPk<1>(rB, rlane(tt, 20), rlane(ss, 20));
    liftPk<2>(rA, rlane(tt, 21), rlane(ss, 21));  liftPk<2>(rB, rlane(tt, 21), rlane(ss, 21));
    liftPk<3>(rA, rlane(tt, 22), rlane(ss, 22));  liftPk<3>(rB, rlane(tt, 22), rlane(ss, 22));
    liftPk<4>(rA, rlane(tt, 23), rlane(ss, 23));  liftPk<4>(rB, rlane(tt, 23), rlane(ss, 23));

    transposePair(rA, rB, ldsA, ldsB, l);        // scalar bit k = qubit k

    // ---- pass 3: qubits 0-5, layer 2 (theta[12..17]) ----
    liftIntra (rA, rlane(tt, 12), rlane(ss, 12)); liftIntra (rB, rlane(tt, 12), rlane(ss, 12));
    liftPk<0>(rA, rlane(tt, 13), rlane(ss, 13));  liftPk<0>(rB, rlane(tt, 13), rlane(ss, 13));
    liftPk<1>(rA, rlane(tt, 14), rlane(ss, 14));  liftPk<1>(rB, rlane(tt, 14), rlane(ss, 14));
    liftPk<2>(rA, rlane(tt, 15), rlane(ss, 15));  liftPk<2>(rB, rlane(tt, 15), rlane(ss, 15));
    liftPk<3>(rA, rlane(tt, 16), rlane(ss, 16));  liftPk<3>(rB, rlane(tt, 16), rlane(ss, 16));
    liftPk<4>(rA, rlane(tt, 17), rlane(ss, 17));  liftPk<4>(rB, rlane(tt, 17), rlane(ss, 17));

    // ---- measurement + interleaved 20-value reduction ----
    float vA[10], vB[10];
    measure(rA, l, vA);
    measure(rB, l, vB);

#pragma unroll
    for (int k = 0; k < KOUT; ++k) {
        float ta = vA[k], tb = vB[k];
#pragma unroll
        for (int off = 32; off >= 1; off >>= 1) {
            ta += __shfl_xor(ta, off, 64);
            tb += __shfl_xor(tb, off, 64);
        }
        vA[k] = ta; vB[k] = tb;
    }

    if (l == 0) {
#pragma unroll
        for (int k = 0; k < KOUT; ++k) {
            out[b * KOUT + k]          = vA[k];
            out[(b + NBLK) * KOUT + k] = vB[k];
        }
    }
}

extern "C" void kernel_launch(void* const* d_in, const int* in_sizes, int n_in,
                              void* d_out, int out_size, void* d_ws, size_t ws_size,
                              hipStream_t stream) {
    const float* x     = (const float*)d_in[0];
    const float* theta = (const float*)d_in[1];
    float* out         = (float*)d_out;
    vqc_kernel<<<NBLK, 64, 0, stream>>>(x, theta, out);
}

// Round 10
// 27.329 us; speedup vs baseline: 1.1704x; 1.1704x over previous
//
#include <hip/hip_runtime.h>
#include <math.h>
#include <stdint.h>

#define DIM  4096
#define KOUT 10
#define BATCH 4096

typedef float float2v __attribute__((ext_vector_type(2)));

// XOR-swizzle on linear LDS float index (verified R1/R4/R6/R8).
__device__ __forceinline__ int swzAddr(int lin) {
    return lin ^ (((lin >> 6) & 7) << 2);
}

__device__ __forceinline__ float rlane(float v, int lane) {
    return __int_as_float(__builtin_amdgcn_readlane(__float_as_int(v), lane));
}

// Drain all pending LDS ops (necessity verified R6): protects the
// phase-0-read -> phase-1-write WAR inside the time-shared transpose.
// (The cross-transpose WAR needs no fence: the next transpose's write DATA
// is produced by gates that consume the prior reads — hard dependency.)
__device__ __forceinline__ void ldsFence() {
    __builtin_amdgcn_sched_barrier(0);
    asm volatile("s_waitcnt lgkmcnt(0)" ::: "memory");
    __builtin_amdgcn_sched_barrier(0);
}

// Packed RY lifting layer on scalar state bit KP+1, full 32-reg array
// (verified R8). t = tan(phi/2), s = sin(phi) (or -cot/-sin => -R; global
// sign cancels in probabilities).
template<int KP>
__device__ __forceinline__ void liftPk(float2v r2[32], float t, float s) {
    const float2v tv = { -t, -t };
    const float2v sv = {  s,  s };
#pragma unroll
    for (int m = 0; m < 16; ++m) {
        const int i0 = ((m >> KP) << (KP + 1)) | (m & ((1 << KP) - 1));
        const int i1 = i0 | (1 << KP);
        float2v a = r2[i0], b = r2[i1];
        float2v a1 = __builtin_elementwise_fma(tv, b, a);
        float2v b1 = __builtin_elementwise_fma(sv, a1, b);
        r2[i1] = b1;
        r2[i0] = __builtin_elementwise_fma(tv, b1, a1);
    }
}

// Half-array variants: operate on 16 float2 regs (32 scalars). Layers on
// state bits 1..4 (KP 0..3) and bit 0 stay within a 32-scalar half.
template<int KP>
__device__ __forceinline__ void liftPkH(float2v* h, float t, float s) {
    const float2v tv = { -t, -t };
    const float2v sv = {  s,  s };
#pragma unroll
    for (int m = 0; m < 8; ++m) {
        const int i0 = ((m >> KP) << (KP + 1)) | (m & ((1 << KP) - 1));
        const int i1 = i0 | (1 << KP);
        float2v a = h[i0], b = h[i1];
        float2v a1 = __builtin_elementwise_fma(tv, b, a);
        float2v b1 = __builtin_elementwise_fma(sv, a1, b);
        h[i1] = b1;
        h[i0] = __builtin_elementwise_fma(tv, b1, a1);
    }
}

__device__ __forceinline__ void liftIntraH(float2v* h, float t, float s) {
#pragma unroll
    for (int m = 0; m < 16; ++m) {
        float a = h[m].x, b = h[m].y;
        float a1 = fmaf(-t, b, a);
        float b1 = fmaf(s, a1, b);
        h[m].x = fmaf(-t, b1, a1);
        h[m].y = b1;
    }
}

// Full-array scalar layer on state bit 0 (verified R8).
__device__ __forceinline__ void liftIntra(float2v r2[32], float t, float s) {
#pragma unroll
    for (int m = 0; m < 32; ++m) {
        float a = r2[m].x, b = r2[m].y;
        float a1 = fmaf(-t, b, a);
        float b1 = fmaf(s, a1, b);
        r2[m].x = fmaf(-t, b1, a1);
        r2[m].y = b1;
    }
}

// 8 KB time-shared lane<->reg transpose, single middle fence (WAR inside).
// Scalar semantics (verified R6/R8): r_new[j]@lane l = r_old[l]@lane j.
__device__ __forceinline__ void transpose64(float2v r2[32], float* lds, int l) {
    float tmp[32];
    if (l < 32) {
#pragma unroll
        for (int e4 = 0; e4 < 16; ++e4)
            *reinterpret_cast<float4*>(&lds[swzAddr(l * 64 + e4 * 4)]) =
                make_float4(r2[2 * e4].x, r2[2 * e4].y,
                            r2[2 * e4 + 1].x, r2[2 * e4 + 1].y);
    }
#pragma unroll
    for (int j = 0; j < 32; ++j)
        tmp[j] = lds[swzAddr(j * 64 + l)];          // new scalars 0..31
    ldsFence();                 // WAR: phase-0 reads must land before overwrite
    if (l >= 32) {
#pragma unroll
        for (int e4 = 0; e4 < 16; ++e4)
            *reinterpret_cast<float4*>(&lds[swzAddr((l - 32) * 64 + e4 * 4)]) =
                make_float4(r2[2 * e4].x, r2[2 * e4].y,
                            r2[2 * e4 + 1].x, r2[2 * e4 + 1].y);
    }
#pragma unroll
    for (int m = 0; m < 16; ++m) {                  // new scalars 32..63
        float2v w;
        w.x = lds[swzAddr((2 * m) * 64 + l)];
        w.y = lds[swzAddr((2 * m + 1) * 64 + l)];
        r2[16 + m] = w;
    }
#pragma unroll
    for (int m = 0; m < 16; ++m) {
        float2v w; w.x = tmp[2 * m]; w.y = tmp[2 * m + 1];
        r2[m] = w;
    }
}

__global__ __launch_bounds__(64) void vqc_kernel(
        const float* __restrict__ x,
        const float* __restrict__ theta,
        float* __restrict__ out)
{
    __shared__ __align__(16) float lds[2048];   // 8 KB
    const int l = threadIdx.x;   // one wave per block, one batch row per block
    const int b = blockIdx.x;

    // Gate params for lifting. RY(theta) rotates by phi = theta/2:
    // t = tan(theta/4), s = sin(theta/2); alt branch -R(phi) keeps |t|<=1.
    float th = theta[l < 24 ? l : 0];
    float qh = 0.25f * th;
    float sq = sinf(qh), cq = cosf(qh);
    float sfull = 2.f * sq * cq;                       // sin(theta/2)
    float tt, ss;
    if (fabsf(sq) <= fabsf(cq)) { tt = sq / cq;  ss = sfull;  }
    else                        { tt = -cq / sq; ss = -sfull; }

    // ---- issue all 16 global loads, then compute halves as data arrives ----
    float2v r2[32];
    const float4* x4 = reinterpret_cast<const float4*>(x + (size_t)b * DIM + l * 64);
#pragma unroll
    for (int e4 = 0; e4 < 16; ++e4) {
        const float4 w = x4[e4];
        float2v lo; lo.x = w.x; lo.y = w.y;
        float2v hi; hi.x = w.z; hi.y = w.w;
        r2[2 * e4]     = lo;
        r2[2 * e4 + 1] = hi;
    }

    // ---- pass 1: qubits 0-5, layer 1. Layers q0-q4 act within each
    //      32-scalar half independently (bit 5 untouched) -> gate half 0
    //      while half 1's loads are still in flight, then half 1, then q5.
    {
        const float t0 = rlane(tt, 0), s0 = rlane(ss, 0);
        const float t1 = rlane(tt, 1), s1 = rlane(ss, 1);
        const float t2 = rlane(tt, 2), s2 = rlane(ss, 2);
        const float t3 = rlane(tt, 3), s3 = rlane(ss, 3);
        const float t4 = rlane(tt, 4), s4 = rlane(ss, 4);
        liftIntraH (r2,      t0, s0);
        liftPkH<0>(r2,       t1, s1);
        liftPkH<1>(r2,       t2, s2);
        liftPkH<2>(r2,       t3, s3);
        liftPkH<3>(r2,       t4, s4);
        liftIntraH (r2 + 16, t0, s0);
        liftPkH<0>(r2 + 16,  t1, s1);
        liftPkH<1>(r2 + 16,  t2, s2);
        liftPkH<2>(r2 + 16,  t3, s3);
        liftPkH<3>(r2 + 16,  t4, s4);
        liftPk<4>(r2, rlane(tt, 5), rlane(ss, 5));   // q5: cross-half pairs
    }

    transpose64(r2, lds, l);                 // scalar bit k = qubit 6+k

    // ---- pass 2: qubits 6-11, layer 1 ----
    liftIntra (r2, rlane(tt, 6),  rlane(ss, 6));
    liftPk<0>(r2, rlane(tt, 7),  rlane(ss, 7));
    liftPk<1>(r2, rlane(tt, 8),  rlane(ss, 8));
    liftPk<2>(r2, rlane(tt, 9),  rlane(ss, 9));
    liftPk<3>(r2, rlane(tt, 10), rlane(ss, 10));
    liftPk<4>(r2, rlane(tt, 11), rlane(ss, 11));

    // CZ diagonal as sign-bit XOR (boolean algebra identical to verified R8
    // select/mul form): flip bit = [base, base^l5, base^l0, base^l5^l0][sel] ^ Ce.
    {
        const int l0 = l & 1, l5 = (l >> 5) & 1;
        const int base = __popc(l & (l >> 1) & 0x1F) & 1;  // pairs among qubits 0-5
        uint32_t U[4];
        U[0] = (uint32_t)base << 31;
        U[1] = (uint32_t)(base ^ l5) << 31;            // e0=1: pair (5,6)
        U[2] = (uint32_t)(base ^ l0) << 31;            // e5=1: pair (0,11)
        U[3] = (uint32_t)(base ^ l5 ^ l0) << 31;
#pragma unroll
        for (int e = 0; e < 64; ++e) {
            const int Ce  = __popc(e & (e >> 1) & 0x1F) & 1;  // pairs among 6-11
            const int sel = (e & 1) | (((e >> 5) & 1) << 1);
            const uint32_t msk = U[sel] ^ (Ce ? 0x80000000u : 0u);
            if (e & 1) r2[e >> 1].y = __uint_as_float(__float_as_uint(r2[e >> 1].y) ^ msk);
            else       r2[e >> 1].x = __uint_as_float(__float_as_uint(r2[e >> 1].x) ^ msk);
        }
    }

    // ---- layer 2 on qubits 6-11 (theta[18..23]) ----
    liftIntra (r2, rlane(tt, 18), rlane(ss, 18));
    liftPk<0>(r2, rlane(tt, 19), rlane(ss, 19));
    liftPk<1>(r2, rlane(tt, 20), rlane(ss, 20));
    liftPk<2>(r2, rlane(tt, 21), rlane(ss, 21));
    liftPk<3>(r2, rlane(tt, 22), rlane(ss, 22));
    liftPk<4>(r2, rlane(tt, 23), rlane(ss, 23));

    transpose64(r2, lds, l);                 // scalar bit k = qubit k

    // ---- pass 3: qubits 0-5, layer 2 (theta[12..17]) ----
    liftIntra (r2, rlane(tt, 12), rlane(ss, 12));
    liftPk<0>(r2, rlane(tt, 13), rlane(ss, 13));
    liftPk<1>(r2, rlane(tt, 14), rlane(ss, 14));
    liftPk<2>(r2, rlane(tt, 15), rlane(ss, 15));
    liftPk<3>(r2, rlane(tt, 16), rlane(ss, 16));
    liftPk<4>(r2, rlane(tt, 17), rlane(ss, 17));

    // ---- measurement (tree verified R7/R8): d = l*64 + j; qubit k<6 =
    //      j-bit k, qubits 6-9 = lane bits 0-3. Square (pk), halving tree.
#pragma unroll
    for (int m = 0; m < 32; ++m) r2[m] *= r2[m];

    float v0 = 0.f, v1 = 0.f, v2 = 0.f, v3 = 0.f, v4 = 0.f;
    float q32[32];
#pragma unroll
    for (int m = 0; m < 32; ++m) { v0 += r2[m].y; q32[m] = r2[m].x + r2[m].y; }
    float q16[16];
#pragma unroll
    for (int m = 0; m < 16; ++m) { v1 += q32[2*m+1]; q16[m] = q32[2*m] + q32[2*m+1]; }
    float q8[8];
#pragma unroll
    for (int m = 0; m < 8; ++m)  { v2 += q16[2*m+1]; q8[m] = q16[2*m] + q16[2*m+1]; }
    float q4[4];
#pragma unroll
    for (int m = 0; m < 4; ++m)  { v3 += q8[2*m+1]; q4[m] = q8[2*m] + q8[2*m+1]; }
    float q2[2];
#pragma unroll
    for (int m = 0; m < 2; ++m)  { v4 += q4[2*m+1]; q2[m] = q4[2*m] + q4[2*m+1]; }
    const float v5   = q2[1];
    const float psum = q2[0] + q2[1];

    float v[10];
    v[0] = v0; v[1] = v1; v[2] = v2; v[3] = v3; v[4] = v4; v[5] = v5;
    v[6] = (l & 1) ? psum : 0.f;
    v[7] = (l & 2) ? psum : 0.f;
    v[8] = (l & 4) ? psum : 0.f;
    v[9] = (l & 8) ? psum : 0.f;

#pragma unroll
    for (int k = 0; k < KOUT; ++k) {
        float t = v[k];
#pragma unroll
        for (int off = 32; off >= 1; off >>= 1)
            t += __shfl_xor(t, off, 64);
        v[k] = t;
    }

    if (l == 0) {
#pragma unroll
        for (int k = 0; k < KOUT; ++k) out[b * KOUT + k] = v[k];
    }
}

extern "C" void kernel_launch(void* const* d_in, const int* in_sizes, int n_in,
                              void* d_out, int out_size, void* d_ws, size_t ws_size,
                              hipStream_t stream) {
    const float* x     = (const float*)d_in[0];
    const float* theta = (const float*)d_in[1];
    float* out         = (float*)d_out;
    vqc_kernel<<<BATCH, 64, 0, stream>>>(x, theta, out);
}